// Round 1
// 790.441 us; speedup vs baseline: 1.0653x; 1.0653x over previous
//
#include <hip/hip_runtime.h>
#include <stdint.h>

// ParallelFcWithAttention: B=16384, F=10, D=512, H=8, DH=64
// kern_attn v2: 512 threads / 8 batch elems per block, 2-phase pipelined B staging
// (stage-next-before-compute, one barrier per slab), MFMA scores, in-register
// shuffle softmax, lane-parallel PV with coalesced O stores.

typedef __bf16 bf16;
typedef __bf16 bf16x8 __attribute__((ext_vector_type(8)));
typedef float f32x4 __attribute__((ext_vector_type(4)));

#define EPS 1e-5f

static constexpr size_t O_ELEMS   = (size_t)16384 * 10 * 512;   // 83,886,080
static constexpr size_t O_BYTES   = O_ELEMS * 2;                // 167,772,160
static constexpr size_t WQKV_ELEMS = (size_t)8 * 192 * 512;     // 786,432
static constexpr size_t WQKV_BYTES = WQKV_ELEMS * 2;

__device__ __forceinline__ void async_copy16(void* lds, const void* g) {
  // wave-uniform LDS base; HW scatters lane i at base + i*16
  __builtin_amdgcn_global_load_lds(
      (const __attribute__((address_space(1))) uint32_t*)g,
      (__attribute__((address_space(3))) uint32_t*)lds, 16, 0, 0);
}

// ---------------- pack weights to bf16 ----------------
// wqkv layout: [h][0:64 = Wq rows h*64.., 64:128 = Wk, 128:192 = Wv][512]
__global__ __launch_bounds__(256) void pack_weights(
    const float* __restrict__ Wq, const float* __restrict__ Wk,
    const float* __restrict__ Wv, const float* __restrict__ Wo,
    bf16* __restrict__ wqkv, bf16* __restrict__ wob) {
  int idx = blockIdx.x * 256 + threadIdx.x;
#pragma unroll
  for (int u = 0; u < 4; ++u) {
    int i = idx + u * 262144;
    if (i < 786432) {
      int pr = i >> 9, k = i & 511;
      int h = pr / 192, w = pr - h * 192;
      int t = w >> 6, r = w & 63;
      const float* src = (t == 0) ? Wq : ((t == 1) ? Wk : Wv);
      wqkv[i] = (bf16)src[(h * 64 + r) * 512 + k];
    } else {
      int j = i - 786432;
      wob[j] = (bf16)Wo[j];
    }
  }
}

// ---------------- fused P + QKV GEMM + attention ----------------
// Workgroup: 8 batch elems -> 80 real rows; M-tiles padded to 96 (wm=1,mt=2 is
// garbage-pad: reads past sA land in valid LDS, outputs discarded at spill).
// Waves: 8 = (wm in 0..1) x (wn in 0..3); per wave 3 M-tiles x 48 N-cols.
// LDS: sA = P [8 slabs][80 rows][8 chunks*16B], chunk XOR-swizzled by row&7. (81920)
//      sB0/sB1 = double-buffered B slab [192 rows][64 k].            (2 x 24576)
//      sQK = q|k spill [88 rows][128 cols] bf16, XOR-swizzled.       (22528)
//      epilogue scratch (v [80][64] bf16 + sc [8][10][12] f32) lives in sB1,
//      which is always the dead buffer at head end (8 slabs/head => parity fixed).
__global__ __launch_bounds__(512, 2) void kern_attn(
    const float* __restrict__ x, const float* __restrict__ Wf,
    const float* __restrict__ bfv, const bf16* __restrict__ wqkv,
    const float* __restrict__ bq, const float* __restrict__ bk,
    const float* __restrict__ bv, bf16* __restrict__ O) {
  __shared__ __align__(16) char sA[8 * 80 * 128];   // 81920
  __shared__ __align__(16) char sB0[24576];
  __shared__ __align__(16) char sB1[24576];
  __shared__ __align__(16) char sQK[88 * 256];      // 22528  (rows 80..87 never written; garbage reads masked)

  bf16* vbuf = (bf16*)sB1;                 // [80][64] bf16 during epilogue
  float* scp = (float*)(sB1 + 10240);      // [8][10][12] f32 attn weights

  const int tid = threadIdx.x;
  const int wave = tid >> 6;
  const int lane = tid & 63;
  const int lm = lane & 15;
  const int lg = lane >> 4;
  const int wm = wave >> 2;
  const int wn = wave & 3;
  const int b0 = blockIdx.x * 8;
  const int lr = lane >> 3;
  const int kcp2 = lane & 7;
  const int kcg = kcp2 ^ lr;               // swizzled global k-chunk for staging

  // ---- prologue: stage (h=0, s=0) into sB0 (hides under P compute) ----
#pragma unroll
  for (int jb = 0; jb < 3; ++jb) {
    int rb = wave + 8 * jb;                // 24 rowblocks of 8 rows
    async_copy16(sB0 + rb * 1024, wqkv + (size_t)(rb * 8 + lr) * 512 + kcg * 8);
  }

  // ---- compute P = relu(x*Wf + bf) into sA (exactly 80 real rows) ----
#pragma unroll
  for (int it = 0; it < 10; ++it) {
    int c = tid + it * 512;                // 5120 chunks: c = s*640 + r*8 + kcp
    int s = c / 640, rem = c - s * 640;
    int r = rem >> 3, kcp = rem & 7;
    int kc = kcp ^ (r & 7);
    int k = s * 64 + kc * 8;
    int bl = r / 10, f = r - bl * 10;
    float xv = x[(b0 + bl) * 10 + f];
    const float* wf = Wf + f * 512 + k;
    const float* bp = bfv + f * 512 + k;
    bf16x8 pv;
#pragma unroll
    for (int j = 0; j < 8; ++j) pv[j] = (bf16)fmaxf(xv * wf[j] + bp[j], 0.f);
    *(bf16x8*)(sA + s * 10240 + r * 128 + kcp * 16) = pv;
  }
  __syncthreads();   // drains prologue staging + P writes

  const int x7 = lm & 7;

  for (int h = 0; h < 8; ++h) {
    f32x4 acc[3][3];
#pragma unroll
    for (int i = 0; i < 3; ++i)
#pragma unroll
      for (int j = 0; j < 3; ++j) { f32x4 z = {0.f, 0.f, 0.f, 0.f}; acc[i][j] = z; }

    for (int s = 0; s < 8; ++s) {
      int t = h * 8 + s;
      char* bufC = (s & 1) ? sB1 : sB0;
      char* bufN = (s & 1) ? sB0 : sB1;
      // issue next slab's staging BEFORE compute (overlaps with ds_read+MFMA)
      if (t != 63) {
        int tn = t + 1;
        int h2 = tn >> 3, s2 = tn & 7;
        const bf16* srcb = wqkv + (size_t)h2 * 98304 + s2 * 64 + kcg * 8;
#pragma unroll
        for (int jb = 0; jb < 3; ++jb) {
          int rb = wave + 8 * jb;
          async_copy16(bufN + rb * 1024, srcb + (size_t)(rb * 8 + lr) * 512);
        }
      }
#pragma unroll
      for (int kk = 0; kk < 2; ++kk) {
        int kcl = kk * 4 + lg;
        int ch = (kcl ^ x7) << 4;          // m&7 == n&7 == lm&7
        bf16x8 af[3], bfr[3];
#pragma unroll
        for (int mt = 0; mt < 3; ++mt) {
          int m = wm * 48 + mt * 16 + lm;  // rows 80..95 garbage-pad (discarded)
          af[mt] = *(const bf16x8*)(sA + s * 10240 + m * 128 + ch);
        }
#pragma unroll
        for (int nt = 0; nt < 3; ++nt) {
          int n = wn * 48 + nt * 16 + lm;
          bfr[nt] = *(const bf16x8*)(bufC + n * 128 + ch);
        }
#pragma unroll
        for (int mt = 0; mt < 3; ++mt)
#pragma unroll
          for (int nt = 0; nt < 3; ++nt)
            acc[mt][nt] = __builtin_amdgcn_mfma_f32_16x16x32_bf16(af[mt], bfr[nt], acc[mt][nt], 0, 0, 0);
      }
      __syncthreads();  // drains next-slab staging; releases bufC for re-stage
    }

    // ---- spill q,k (+bias) -> sQK (swizzled), v (+bias) -> vbuf ----
    {
      float bias[3];
#pragma unroll
      for (int nt = 0; nt < 3; ++nt) {
        int col = wn * 48 + nt * 16 + lm;
        bias[nt] = (col < 64) ? bq[h * 64 + col]
                 : (col < 128) ? bk[h * 64 + col - 64]
                 : bv[h * 64 + col - 128];
      }
#pragma unroll
      for (int mt = 0; mt < 3; ++mt) {
        int rowb = wm * 48 + mt * 16 + lg * 4;
        if (rowb < 80) {
#pragma unroll
          for (int r = 0; r < 4; ++r) {
            int rw = rowb + r;
#pragma unroll
            for (int nt = 0; nt < 3; ++nt) {
              int col = wn * 48 + nt * 16 + lm;
              float val = acc[mt][nt][r] + bias[nt];
              if (col < 128)
                *(bf16*)(sQK + rw * 256 + (((col >> 3) ^ (rw & 7)) << 4) + (col & 7) * 2) = (bf16)val;
              else
                vbuf[rw * 64 + (col - 128)] = (bf16)val;
            }
          }
        }
      }
    }
    __syncthreads();

    // ---- scores via MFMA (wave = local batch), softmax in-register ----
    {
      const int b = wave;
      f32x4 sv = {0.f, 0.f, 0.f, 0.f};
      const int rowa = b * 10 + lm;        // lm>=10: garbage rows/cols, masked below
      const int x7r = rowa & 7;
#pragma unroll
      for (int kk = 0; kk < 2; ++kk) {
        bf16x8 qf = *(const bf16x8*)(sQK + rowa * 256 + (((kk * 4 + lg) ^ x7r) << 4));
        bf16x8 kf = *(const bf16x8*)(sQK + rowa * 256 + (((8 + kk * 4 + lg) ^ x7r) << 4));
        sv = __builtin_amdgcn_mfma_f32_16x16x32_bf16(qf, kf, sv, 0, 0, 0);
      }
      // C layout: row i = lg*4+r, col j = lm. softmax over j = shuffle over 16-lane group.
#pragma unroll
      for (int r = 0; r < 4; ++r) {
        float val = (lm < 10) ? sv[r] * 0.125f : -1e30f;   // mask pad cols (also kills garbage)
        float mx = val;
#pragma unroll
        for (int off = 1; off < 16; off <<= 1) mx = fmaxf(mx, __shfl_xor(mx, off));
        float e = __expf(val - mx);
        float ssum = e;
#pragma unroll
        for (int off = 1; off < 16; off <<= 1) ssum += __shfl_xor(ssum, off);
        int i = lg * 4 + r;
        if (i < 10 && lm < 12) scp[(b * 10 + i) * 12 + lm] = e / ssum;
      }
    }

    // ---- PV (lane <-> d), coalesced O store (wave-local; no barrier needed) ----
    {
      const int b = wave;
      const int d = lane;                  // 0..63
      float vv[10];
#pragma unroll
      for (int j = 0; j < 10; ++j) vv[j] = (float)vbuf[(b * 10 + j) * 64 + d];
      bf16* Ob = O + ((size_t)(b0 + b) * 10) * 512 + h * 64 + d;
#pragma unroll
      for (int i = 0; i < 10; ++i) {
        const float* ar = scp + (b * 10 + i) * 12;
        f32x4 a0 = *(const f32x4*)ar;
        f32x4 a1 = *(const f32x4*)(ar + 4);
        float o = a0[0] * vv[0] + a0[1] * vv[1] + a0[2] * vv[2] + a0[3] * vv[3]
                + a1[0] * vv[4] + a1[1] * vv[5] + a1[2] * vv[6] + a1[3] * vv[7]
                + ar[8] * vv[8] + ar[9] * vv[9];
        Ob[(size_t)i * 512] = (bf16)o;     // 64 lanes x 2B = 128B contiguous
      }
    }
    __syncthreads();  // protect vbuf/scp (in sB1) before next head stages into it
  }
}

// ---------------- O @ Wo.T + bo -> LayerNorm -> sum over F ----------------
// Workgroup: 4 batch elems (40 rows + 8 pad), full N=512 so LN sees whole rows.
__global__ __launch_bounds__(256, 2) void kern_out(
    const bf16* __restrict__ O, const bf16* __restrict__ wob,
    const float* __restrict__ bo, const float* __restrict__ gamma,
    const float* __restrict__ beta, float* __restrict__ out) {
  __shared__ __align__(16) char sAB[71680];  // A slab @0 (6144) | B slab @6144 (65536); epilogue: ln bf16 [48][520]
  __shared__ float partial[48][4][2];
  __shared__ float stats[48][2];
  char* As = sAB;
  char* Bs = sAB + 6144;
  bf16* lnb = (bf16*)sAB;

  const int tid = threadIdx.x;
  const int wave = tid >> 6, lane = tid & 63;
  const int lm = lane & 15, lg = lane >> 4;
  const int m0 = blockIdx.x * 40;

  f32x4 acc[3][8];
#pragma unroll
  for (int i = 0; i < 3; ++i)
#pragma unroll
    for (int j = 0; j < 8; ++j) { f32x4 z = {0.f, 0.f, 0.f, 0.f}; acc[i][j] = z; }

  const int lr = lane >> 3;
  const int kcp2 = lane & 7;
  const int kcg = kcp2 ^ lr;

  for (int s = 0; s < 8; ++s) {
    {  // stage A: 6 rowblocks (48 rows), clamp pad rows to row 39
      int rr = wave * 8 + lr;
      int rm = min(rr, 39);
      async_copy16(As + wave * 1024, O + (size_t)(m0 + rm) * 512 + s * 64 + kcg * 8);
      if (wave < 2) {
        int rr2 = (4 + wave) * 8 + lr;
        int rm2 = min(rr2, 39);
        async_copy16(As + (4 + wave) * 1024, O + (size_t)(m0 + rm2) * 512 + s * 64 + kcg * 8);
      }
    }
    // stage B: Wo slab, 64 rowblocks, 16 per wave
#pragma unroll
    for (int jb = 0; jb < 16; ++jb) {
      int rb = wave + 4 * jb;
      int n = rb * 8 + lr;
      async_copy16(Bs + rb * 1024, wob + (size_t)n * 512 + s * 64 + kcg * 8);
    }
    __syncthreads();
#pragma unroll
    for (int kk = 0; kk < 2; ++kk) {
      int kcl = kk * 4 + lg;
      bf16x8 af[3], bfr[8];
#pragma unroll
      for (int mt = 0; mt < 3; ++mt) {
        int m = mt * 16 + lm;
        af[mt] = *(const bf16x8*)(As + m * 128 + ((kcl ^ (m & 7)) << 4));
      }
#pragma unroll
      for (int nt = 0; nt < 8; ++nt) {
        int n = wave * 128 + nt * 16 + lm;
        bfr[nt] = *(const bf16x8*)(Bs + n * 128 + ((kcl ^ (n & 7)) << 4));
      }
#pragma unroll
      for (int mt = 0; mt < 3; ++mt)
#pragma unroll
        for (int nt = 0; nt < 8; ++nt)
          acc[mt][nt] = __builtin_amdgcn_mfma_f32_16x16x32_bf16(af[mt], bfr[nt], acc[mt][nt], 0, 0, 0);
    }
    __syncthreads();
  }

  // + bias
#pragma unroll
  for (int nt = 0; nt < 8; ++nt) {
    int col = wave * 128 + nt * 16 + lm;
    float bb = bo[col];
#pragma unroll
    for (int mt = 0; mt < 3; ++mt)
#pragma unroll
      for (int r = 0; r < 4; ++r) acc[mt][nt][r] += bb;
  }

  // per-row mean/var: lane-local over 8 nt, then xor-shuffle across the 16-lane col group
#pragma unroll
  for (int mt = 0; mt < 3; ++mt)
#pragma unroll
    for (int r = 0; r < 4; ++r) {
      float s1 = 0.f, s2 = 0.f;
#pragma unroll
      for (int nt = 0; nt < 8; ++nt) { float v = acc[mt][nt][r]; s1 += v; s2 += v * v; }
#pragma unroll
      for (int off = 1; off < 16; off <<= 1) {
        s1 += __shfl_xor(s1, off);
        s2 += __shfl_xor(s2, off);
      }
      if (lm == 0) {
        int row = mt * 16 + lg * 4 + r;
        partial[row][wave][0] = s1;
        partial[row][wave][1] = s2;
      }
    }
  __syncthreads();
  if (tid < 48) {
    float s1 = partial[tid][0][0] + partial[tid][1][0] + partial[tid][2][0] + partial[tid][3][0];
    float s2 = partial[tid][0][1] + partial[tid][1][1] + partial[tid][2][1] + partial[tid][3][1];
    float mu = s1 * (1.f / 512.f);
    float var = s2 * (1.f / 512.f) - mu * mu;
    stats[tid][0] = mu;
    stats[tid][1] = rsqrtf(var + EPS);
  }
  __syncthreads();
  // normalized values -> LDS bf16 (GEMM buffers dead now), stride 520 to break bank alias
#pragma unroll
  for (int mt = 0; mt < 3; ++mt)
#pragma unroll
    for (int r = 0; r < 4; ++r) {
      int row = mt * 16 + lg * 4 + r;
      float mu = stats[row][0], rr = stats[row][1];
#pragma unroll
      for (int nt = 0; nt < 8; ++nt) {
        int col = wave * 128 + nt * 16 + lm;
        lnb[row * 520 + col] = (bf16)((acc[mt][nt][r] - mu) * rr);
      }
    }
  __syncthreads();
  // out[b,n] = gamma[n]*sum_f lnv + 10*beta[n]
#pragma unroll
  for (int u = 0; u < 8; ++u) {
    int id = tid + u * 256;
    int b = id >> 9, n = id & 511;
    float ssum = 0.f;
#pragma unroll
    for (int f = 0; f < 10; ++f) ssum += (float)lnb[(b * 10 + f) * 520 + n];
    out[(size_t)(blockIdx.x * 4 + b) * 512 + n] = gamma[n] * ssum + 10.f * beta[n];
  }
}

extern "C" void kernel_launch(void* const* d_in, const int* in_sizes, int n_in,
                              void* d_out, int out_size, void* d_ws, size_t ws_size,
                              hipStream_t stream) {
  const float* x     = (const float*)d_in[0];
  const float* Wf    = (const float*)d_in[1];
  const float* bfv   = (const float*)d_in[2];
  const float* Wq    = (const float*)d_in[3];
  const float* Wk    = (const float*)d_in[4];
  const float* Wv    = (const float*)d_in[5];
  const float* bq    = (const float*)d_in[6];
  const float* bk    = (const float*)d_in[7];
  const float* bv    = (const float*)d_in[8];
  const float* Wo    = (const float*)d_in[9];
  const float* bo    = (const float*)d_in[10];
  const float* gamma = (const float*)d_in[11];
  const float* beta  = (const float*)d_in[12];
  float* out = (float*)d_out;

  char* ws = (char*)d_ws;
  bf16* O    = (bf16*)ws;                              // 167,772,160 B
  bf16* wqkv = (bf16*)(ws + O_BYTES);                  // 1,572,864 B
  bf16* wob  = (bf16*)(ws + O_BYTES + WQKV_BYTES);     // 524,288 B

  pack_weights<<<1024, 256, 0, stream>>>(Wq, Wk, Wv, Wo, wqkv, wob);
  kern_attn<<<2048, 512, 0, stream>>>(x, Wf, bfv, wqkv, bq, bk, bv, O);
  kern_out<<<4096, 256, 0, stream>>>(O, wob, bo, gamma, beta, out);
}

// Round 2
// 755.802 us; speedup vs baseline: 1.1142x; 1.0458x over previous
//
#include <hip/hip_runtime.h>
#include <stdint.h>

// ParallelFcWithAttention: B=16384, F=10, D=512, H=8, DH=64
// v3: single fused kernel. Phase 1 = P+QKV GEMM+attention (v2 structure) with
// cross-barrier A-frag prefetch, setprio around MFMA, pad-row work trimmed.
// Phase 2 = Wo GEMM + LN + sum over F, fused in-block (O stays L2-hot, same rows).

typedef __bf16 bf16;
typedef __bf16 bf16x8 __attribute__((ext_vector_type(8)));
typedef float f32x4 __attribute__((ext_vector_type(4)));

#define EPS 1e-5f

static constexpr size_t O_ELEMS   = (size_t)16384 * 10 * 512;   // 83,886,080
static constexpr size_t O_BYTES   = O_ELEMS * 2;                // 167,772,160
static constexpr size_t WQKV_BYTES = (size_t)8 * 192 * 512 * 2; // 1,572,864

__device__ __forceinline__ void async_copy16(void* lds, const void* g) {
  // wave-uniform LDS base; HW scatters lane i at base + i*16
  __builtin_amdgcn_global_load_lds(
      (const __attribute__((address_space(1))) uint32_t*)g,
      (__attribute__((address_space(3))) uint32_t*)lds, 16, 0, 0);
}

// ---------------- pack weights to bf16 ----------------
// wqkv layout: [h][0:64 = Wq rows h*64.., 64:128 = Wk, 128:192 = Wv][512]
__global__ __launch_bounds__(256) void pack_weights(
    const float* __restrict__ Wq, const float* __restrict__ Wk,
    const float* __restrict__ Wv, const float* __restrict__ Wo,
    bf16* __restrict__ wqkv, bf16* __restrict__ wob) {
  int idx = blockIdx.x * 256 + threadIdx.x;
#pragma unroll
  for (int u = 0; u < 4; ++u) {
    int i = idx + u * 262144;
    if (i < 786432) {
      int pr = i >> 9, k = i & 511;
      int h = pr / 192, w = pr - h * 192;
      int t = w >> 6, r = w & 63;
      const float* src = (t == 0) ? Wq : ((t == 1) ? Wk : Wv);
      wqkv[i] = (bf16)src[(h * 64 + r) * 512 + k];
    } else {
      int j = i - 786432;
      wob[j] = (bf16)Wo[j];
    }
  }
}

// ---------------- fused kernel ----------------
// 512 threads, 8 batch elems (80 rows) per block. 1 block/CU (LDS 150KiB).
// LDS pool carve:
//   phase 1: sA  @0      [8 slabs][80 rows][128B]      81920
//            sB0 @81920  B slab dbuf A                 24576
//            sB1 @106496 B slab dbuf B (epilogue: vbuf+scp)
//            sQK @131072 [88][256] q|k spill           22528  (end 153600)
//   phase 2: Ab @0 (10240) | Bb @12288 (65536) | lnb @0 [80][520] bf16 (83200)
//            partial @145920 [96][4][2] f32 | stats @148992 [80][2] f32
__global__ __launch_bounds__(512, 2) void kern_fused(
    const float* __restrict__ x, const float* __restrict__ Wf,
    const float* __restrict__ bfv, const bf16* __restrict__ wqkv,
    const float* __restrict__ bq, const float* __restrict__ bk,
    const float* __restrict__ bv, bf16* __restrict__ O,
    const bf16* __restrict__ wob, const float* __restrict__ bo,
    const float* __restrict__ gamma, const float* __restrict__ beta,
    float* __restrict__ out) {
  __shared__ __align__(16) char smem[153600];
  char* sA  = smem;
  char* sB0 = smem + 81920;
  char* sB1 = smem + 106496;
  char* sQK = smem + 131072;
  bf16* vbuf = (bf16*)sB1;                 // [80][64] bf16 during epilogue
  float* scp = (float*)(sB1 + 10240);      // [8][10][12] f32 attn weights

  const int tid = threadIdx.x;
  const int wave = tid >> 6;
  const int lane = tid & 63;
  const int lm = lane & 15;
  const int lg = lane >> 4;
  const int wm = wave >> 2;
  const int wn = wave & 3;
  const int b0 = blockIdx.x * 8;
  const int lr = lane >> 3;
  const int kcg = (lane & 7) ^ lr;         // swizzled global k-chunk for staging
  const int x7 = lm & 7;

  // ---- prologue: stage (h=0, s=0) into sB0 (hides under P compute) ----
#pragma unroll
  for (int jb = 0; jb < 3; ++jb) {
    int rb = wave + 8 * jb;                // 24 rowblocks of 8 rows
    async_copy16(sB0 + rb * 1024, wqkv + (size_t)(rb * 8 + lr) * 512 + kcg * 8);
  }

  // ---- compute P = relu(x*Wf + bf) into sA (80 real rows, no pad) ----
#pragma unroll
  for (int it = 0; it < 10; ++it) {
    int c = tid + it * 512;                // 5120 chunks: c = s*640 + r*8 + kcp
    int s = c / 640, rem = c - s * 640;
    int r = rem >> 3, kcp = rem & 7;
    int kc = kcp ^ (r & 7);
    int k = s * 64 + kc * 8;
    int bl = r / 10, f = r - bl * 10;
    float xv = x[(b0 + bl) * 10 + f];
    const float* wf = Wf + f * 512 + k;
    const float* bp = bfv + f * 512 + k;
    bf16x8 pv;
#pragma unroll
    for (int j = 0; j < 8; ++j) pv[j] = (bf16)fmaxf(xv * wf[j] + bp[j], 0.f);
    *(bf16x8*)(sA + s * 10240 + r * 128 + kcp * 16) = pv;
  }
  __syncthreads();   // drains prologue staging + P writes

  // ---- A-frag prefetch registers (slab 0) ----
  bf16x8 af[2][3];
#pragma unroll
  for (int kk = 0; kk < 2; ++kk)
#pragma unroll
    for (int mt = 0; mt < 3; ++mt)
      if (mt < 2 || wm == 0) {
        int m = wm * 48 + mt * 16 + lm;    // wm=1 covers rows 48..79 only (mt<2)
        af[kk][mt] = *(const bf16x8*)(sA + m * 128 + (((kk * 4 + lg) ^ x7) << 4));
      }

  for (int h = 0; h < 8; ++h) {
    f32x4 acc[3][3];
#pragma unroll
    for (int i = 0; i < 3; ++i)
#pragma unroll
      for (int j = 0; j < 3; ++j) { f32x4 z = {0.f, 0.f, 0.f, 0.f}; acc[i][j] = z; }

    for (int s = 0; s < 8; ++s) {
      int t = h * 8 + s;
      char* bufC = (s & 1) ? sB1 : sB0;
      char* bufN = (s & 1) ? sB0 : sB1;
      // issue next slab's staging BEFORE compute (overlaps with ds_read+MFMA)
      if (t != 63) {
        int tn = t + 1;
        int h2 = tn >> 3, s2 = tn & 7;
        const bf16* srcb = wqkv + (size_t)h2 * 98304 + s2 * 64 + kcg * 8;
#pragma unroll
        for (int jb = 0; jb < 3; ++jb) {
          int rb = wave + 8 * jb;
          async_copy16(bufN + rb * 1024, srcb + (size_t)(rb * 8 + lr) * 512);
        }
      }
#pragma unroll
      for (int kk = 0; kk < 2; ++kk) {
        int ch = ((kk * 4 + lg) ^ x7) << 4;   // m&7 == n&7 == lm&7
        bf16x8 bfr[3];
#pragma unroll
        for (int nt = 0; nt < 3; ++nt) {
          int n = wn * 48 + nt * 16 + lm;
          bfr[nt] = *(const bf16x8*)(bufC + n * 128 + ch);
        }
        __builtin_amdgcn_s_setprio(1);
#pragma unroll
        for (int mt = 0; mt < 3; ++mt)
          if (mt < 2 || wm == 0)
#pragma unroll
            for (int nt = 0; nt < 3; ++nt)
              acc[mt][nt] = __builtin_amdgcn_mfma_f32_16x16x32_bf16(af[kk][mt], bfr[nt], acc[mt][nt], 0, 0, 0);
        __builtin_amdgcn_s_setprio(0);
      }
      // prefetch next slab's A-frags BEFORE the barrier (sA is immutable;
      // (s+1)&7 wraps to slab 0 for the next head)
      {
        const char* sAn = sA + ((s + 1) & 7) * 10240;
#pragma unroll
        for (int kk = 0; kk < 2; ++kk)
#pragma unroll
          for (int mt = 0; mt < 3; ++mt)
            if (mt < 2 || wm == 0) {
              int m = wm * 48 + mt * 16 + lm;
              af[kk][mt] = *(const bf16x8*)(sAn + m * 128 + (((kk * 4 + lg) ^ x7) << 4));
            }
      }
      __syncthreads();  // drains next-slab staging; releases bufC for re-stage
    }

    // ---- spill q,k (+bias) -> sQK (swizzled), v (+bias) -> vbuf ----
    {
      float bias[3];
#pragma unroll
      for (int nt = 0; nt < 3; ++nt) {
        int col = wn * 48 + nt * 16 + lm;
        bias[nt] = (col < 64) ? bq[h * 64 + col]
                 : (col < 128) ? bk[h * 64 + col - 64]
                 : bv[h * 64 + col - 128];
      }
#pragma unroll
      for (int mt = 0; mt < 3; ++mt) {
        int rowb = wm * 48 + mt * 16 + lg * 4;
        if (rowb < 80) {
#pragma unroll
          for (int r = 0; r < 4; ++r) {
            int rw = rowb + r;
#pragma unroll
            for (int nt = 0; nt < 3; ++nt) {
              int col = wn * 48 + nt * 16 + lm;
              float val = acc[mt][nt][r] + bias[nt];
              if (col < 128)
                *(bf16*)(sQK + rw * 256 + (((col >> 3) ^ (rw & 7)) << 4) + (col & 7) * 2) = (bf16)val;
              else
                vbuf[rw * 64 + (col - 128)] = (bf16)val;
            }
          }
        }
      }
    }
    __syncthreads();

    // ---- scores via MFMA (wave = local batch), softmax in-register ----
    {
      const int b = wave;
      f32x4 sv = {0.f, 0.f, 0.f, 0.f};
      const int rowa = b * 10 + lm;        // lm>=10: garbage rows/cols, masked below
      const int x7r = rowa & 7;
#pragma unroll
      for (int kk = 0; kk < 2; ++kk) {
        bf16x8 qf = *(const bf16x8*)(sQK + rowa * 256 + (((kk * 4 + lg) ^ x7r) << 4));
        bf16x8 kf = *(const bf16x8*)(sQK + rowa * 256 + (((8 + kk * 4 + lg) ^ x7r) << 4));
        sv = __builtin_amdgcn_mfma_f32_16x16x32_bf16(qf, kf, sv, 0, 0, 0);
      }
      // C layout: row i = lg*4+r, col j = lm. softmax over j = shuffle over 16-lane group.
#pragma unroll
      for (int r = 0; r < 4; ++r) {
        float val = (lm < 10) ? sv[r] * 0.125f : -1e30f;   // mask pad cols
        float mx = val;
#pragma unroll
        for (int off = 1; off < 16; off <<= 1) mx = fmaxf(mx, __shfl_xor(mx, off));
        float e = __expf(val - mx);
        float ssum = e;
#pragma unroll
        for (int off = 1; off < 16; off <<= 1) ssum += __shfl_xor(ssum, off);
        int i = lg * 4 + r;
        if (i < 10 && lm < 12) scp[(b * 10 + i) * 12 + lm] = e / ssum;
      }
    }

    // ---- PV (lane <-> d), coalesced O store (wave-local; no barrier needed) ----
    {
      const int b = wave;
      const int d = lane;                  // 0..63
      float vv[10];
#pragma unroll
      for (int j = 0; j < 10; ++j) vv[j] = (float)vbuf[(b * 10 + j) * 64 + d];
      bf16* Ob = O + ((size_t)(b0 + b) * 10) * 512 + h * 64 + d;
#pragma unroll
      for (int i = 0; i < 10; ++i) {
        const float* ar = scp + (b * 10 + i) * 12;
        f32x4 a0 = *(const f32x4*)ar;
        f32x4 a1 = *(const f32x4*)(ar + 4);
        float o = a0[0] * vv[0] + a0[1] * vv[1] + a0[2] * vv[2] + a0[3] * vv[3]
                + a1[0] * vv[4] + a1[1] * vv[5] + a1[2] * vv[6] + a1[3] * vv[7]
                + ar[8] * vv[8] + ar[9] * vv[9];
        Ob[(size_t)i * 512] = (bf16)o;     // 64 lanes x 2B = 128B contiguous
      }
    }
    __syncthreads();  // protect vbuf/scp (in sB1) before next head's staging
  }

  // ================= Phase 2: O @ Wo^T + bo -> LN -> sum over F =================
  // Same 80 rows this block just wrote (L2-hot). LDS phase-1 regions all dead.
  {
    char* Ab = smem;                        // [80 rows][64k] staged slab, 10240
    char* Bb = smem + 12288;                // [512 rows][64k], 65536
    float* partial = (float*)(smem + 145920); // [96][4][2]
    float* stats   = (float*)(smem + 148992); // [80][2]
    const bf16* Osrc = O + (size_t)blockIdx.x * 80 * 512;

    f32x4 acc[3][8];
#pragma unroll
    for (int i = 0; i < 3; ++i)
#pragma unroll
      for (int j = 0; j < 8; ++j) { f32x4 z = {0.f, 0.f, 0.f, 0.f}; acc[i][j] = z; }

    for (int s = 0; s < 8; ++s) {
      // stage A: 10 rowblocks (80 rows)
      async_copy16(Ab + wave * 1024, Osrc + (size_t)(wave * 8 + lr) * 512 + s * 64 + kcg * 8);
      if (wave < 2) {
        int rb2 = 8 + wave;
        async_copy16(Ab + rb2 * 1024, Osrc + (size_t)(rb2 * 8 + lr) * 512 + s * 64 + kcg * 8);
      }
      // stage B: wob slab, 64 rowblocks, 8 per wave
#pragma unroll
      for (int jb = 0; jb < 8; ++jb) {
        int rb = wave + 8 * jb;
        async_copy16(Bb + rb * 1024, wob + (size_t)(rb * 8 + lr) * 512 + s * 64 + kcg * 8);
      }
      __syncthreads();
#pragma unroll
      for (int kk = 0; kk < 2; ++kk) {
        int ch = ((kk * 4 + lg) ^ x7) << 4;
        bf16x8 a2[3], b2[8];
#pragma unroll
        for (int mt = 0; mt < 3; ++mt)
          if (mt < 2 || wm == 0)
            a2[mt] = *(const bf16x8*)(Ab + (wm * 48 + mt * 16 + lm) * 128 + ch);
#pragma unroll
        for (int nt = 0; nt < 8; ++nt)
          b2[nt] = *(const bf16x8*)(Bb + (wn * 128 + nt * 16 + lm) * 128 + ch);
        __builtin_amdgcn_s_setprio(1);
#pragma unroll
        for (int mt = 0; mt < 3; ++mt)
          if (mt < 2 || wm == 0)
#pragma unroll
            for (int nt = 0; nt < 8; ++nt)
              acc[mt][nt] = __builtin_amdgcn_mfma_f32_16x16x32_bf16(a2[mt], b2[nt], acc[mt][nt], 0, 0, 0);
        __builtin_amdgcn_s_setprio(0);
      }
      __syncthreads();
    }

    // + bias
#pragma unroll
    for (int nt = 0; nt < 8; ++nt) {
      float bb = bo[wn * 128 + nt * 16 + lm];
#pragma unroll
      for (int mt = 0; mt < 3; ++mt)
#pragma unroll
        for (int r = 0; r < 4; ++r) acc[mt][nt][r] += bb;
    }

    // per-row mean/var: lane-local over 8 nt, then xor-shuffle across 16-lane col group
#pragma unroll
    for (int mt = 0; mt < 3; ++mt)
#pragma unroll
      for (int r = 0; r < 4; ++r) {
        float s1 = 0.f, s2 = 0.f;
#pragma unroll
        for (int nt = 0; nt < 8; ++nt) { float v = acc[mt][nt][r]; s1 += v; s2 += v * v; }
#pragma unroll
        for (int off = 1; off < 16; off <<= 1) {
          s1 += __shfl_xor(s1, off);
          s2 += __shfl_xor(s2, off);
        }
        if (lm == 0) {
          int row = wm * 48 + mt * 16 + lg * 4 + r;
          if (row < 80) {
            partial[(row * 4 + wn) * 2]     = s1;
            partial[(row * 4 + wn) * 2 + 1] = s2;
          }
        }
      }
    __syncthreads();
    if (tid < 80) {
      float s1 = 0.f, s2 = 0.f;
#pragma unroll
      for (int w = 0; w < 4; ++w) {
        s1 += partial[(tid * 4 + w) * 2];
        s2 += partial[(tid * 4 + w) * 2 + 1];
      }
      float mu = s1 * (1.f / 512.f);
      float var = s2 * (1.f / 512.f) - mu * mu;
      stats[tid * 2]     = mu;
      stats[tid * 2 + 1] = rsqrtf(var + EPS);
    }
    __syncthreads();
    // normalized values -> LDS bf16 (GEMM buffers dead), stride 520 to break bank alias
    bf16* lnb = (bf16*)smem;
#pragma unroll
    for (int mt = 0; mt < 3; ++mt)
#pragma unroll
      for (int r = 0; r < 4; ++r) {
        int row = wm * 48 + mt * 16 + lg * 4 + r;
        if (row < 80) {
          float mu = stats[row * 2], rr = stats[row * 2 + 1];
#pragma unroll
          for (int nt = 0; nt < 8; ++nt) {
            int col = wn * 128 + nt * 16 + lm;
            lnb[row * 520 + col] = (bf16)((acc[mt][nt][r] - mu) * rr);
          }
        }
      }
    __syncthreads();
    // out[b,n] = gamma[n]*sum_f lnv + 10*beta[n]
#pragma unroll
    for (int u = 0; u < 8; ++u) {
      int id = tid + u * 512;              // 4096 outputs: 8b x 512n
      int b = id >> 9, n = id & 511;
      float ssum = 0.f;
#pragma unroll
      for (int f = 0; f < 10; ++f) ssum += (float)lnb[(b * 10 + f) * 520 + n];
      out[((size_t)blockIdx.x * 8 + b) * 512 + n] = gamma[n] * ssum + 10.f * beta[n];
    }
  }
}

extern "C" void kernel_launch(void* const* d_in, const int* in_sizes, int n_in,
                              void* d_out, int out_size, void* d_ws, size_t ws_size,
                              hipStream_t stream) {
  const float* x     = (const float*)d_in[0];
  const float* Wf    = (const float*)d_in[1];
  const float* bfv   = (const float*)d_in[2];
  const float* Wq    = (const float*)d_in[3];
  const float* Wk    = (const float*)d_in[4];
  const float* Wv    = (const float*)d_in[5];
  const float* bq    = (const float*)d_in[6];
  const float* bk    = (const float*)d_in[7];
  const float* bv    = (const float*)d_in[8];
  const float* Wo    = (const float*)d_in[9];
  const float* bo    = (const float*)d_in[10];
  const float* gamma = (const float*)d_in[11];
  const float* beta  = (const float*)d_in[12];
  float* out = (float*)d_out;

  char* ws = (char*)d_ws;
  bf16* O    = (bf16*)ws;                              // 167,772,160 B
  bf16* wqkv = (bf16*)(ws + O_BYTES);                  // 1,572,864 B
  bf16* wob  = (bf16*)(ws + O_BYTES + WQKV_BYTES);     // 524,288 B

  pack_weights<<<1024, 256, 0, stream>>>(Wq, Wk, Wv, Wo, wqkv, wob);
  kern_fused<<<2048, 512, 0, stream>>>(x, Wf, bfv, wqkv, bq, bk, bv, O,
                                       wob, bo, gamma, beta, out);
}

// Round 3
// 709.168 us; speedup vs baseline: 1.1874x; 1.0658x over previous
//
#include <hip/hip_runtime.h>
#include <stdint.h>

// ParallelFcWithAttention: B=16384, F=10, D=512, H=8, DH=64
// v4: raw s_barrier + counted vmcnt (T3/T4) in both GEMM loops so staged
// global_load_lds stay in flight across barriers (no vmcnt(0) drain).
// Phase 2 rebuilt: BK=32, double-buffered A and B slabs, paired-row LDS
// layout (2 rows/128B line, XOR-swizzled granules; pre-swizzled source).

typedef __bf16 bf16;
typedef __bf16 bf16x8 __attribute__((ext_vector_type(8)));
typedef float f32x4 __attribute__((ext_vector_type(4)));

#define EPS 1e-5f

static constexpr size_t O_ELEMS   = (size_t)16384 * 10 * 512;   // 83,886,080
static constexpr size_t O_BYTES   = O_ELEMS * 2;                // 167,772,160
static constexpr size_t WQKV_BYTES = (size_t)8 * 192 * 512 * 2; // 1,572,864

__device__ __forceinline__ void async_copy16(void* lds, const void* g) {
  // wave-uniform LDS base; HW scatters lane i at base + i*16; global addr per-lane
  __builtin_amdgcn_global_load_lds(
      (const __attribute__((address_space(1))) uint32_t*)g,
      (__attribute__((address_space(3))) uint32_t*)lds, 16, 0, 0);
}

// ---------------- pack weights to bf16 ----------------
// wqkv layout: [h][0:64 = Wq rows h*64.., 64:128 = Wk, 128:192 = Wv][512]
__global__ __launch_bounds__(256) void pack_weights(
    const float* __restrict__ Wq, const float* __restrict__ Wk,
    const float* __restrict__ Wv, const float* __restrict__ Wo,
    bf16* __restrict__ wqkv, bf16* __restrict__ wob) {
  int idx = blockIdx.x * 256 + threadIdx.x;
#pragma unroll
  for (int u = 0; u < 4; ++u) {
    int i = idx + u * 262144;
    if (i < 786432) {
      int pr = i >> 9, k = i & 511;
      int h = pr / 192, w = pr - h * 192;
      int t = w >> 6, r = w & 63;
      const float* src = (t == 0) ? Wq : ((t == 1) ? Wk : Wv);
      wqkv[i] = (bf16)src[(h * 64 + r) * 512 + k];
    } else {
      int j = i - 786432;
      wob[j] = (bf16)Wo[j];
    }
  }
}

// ---------------- fused kernel ----------------
// 512 threads, 8 batch elems (80 rows) per block. 1 block/CU (LDS 150KiB).
// phase 1: sA @0 [8 slabs][80][128B] 81920 | sB0 @81920 | sB1 @106496 (24576 each)
//          sQK @131072 [88][256] 22528. vbuf+scp live in sB1 at head epilogue
//          (8 slabs/head => at head end the in-flight stage targets sB0).
// phase 2: Ab0 @0, Ab1 @5120 ([80][32k] each, paired-row layout)
//          Bb0 @10240, Bb1 @43008 ([512][32k] each, 32768)
//          lnb @0 [80][520] bf16 (dead-GEMM overlay), partial @145920, stats @148992
__global__ __launch_bounds__(512, 2) void kern_fused(
    const float* __restrict__ x, const float* __restrict__ Wf,
    const float* __restrict__ bfv, const bf16* __restrict__ wqkv,
    const float* __restrict__ bq, const float* __restrict__ bk,
    const float* __restrict__ bv, bf16* __restrict__ O,
    const bf16* __restrict__ wob, const float* __restrict__ bo,
    const float* __restrict__ gamma, const float* __restrict__ beta,
    float* __restrict__ out) {
  __shared__ __align__(16) char smem[153600];
  char* sA  = smem;
  char* sB0 = smem + 81920;
  char* sB1 = smem + 106496;
  char* sQK = smem + 131072;
  bf16* vbuf = (bf16*)sB1;                 // [80][64] bf16 during epilogue
  float* scp = (float*)(sB1 + 10240);      // [8][10][12] f32 attn weights

  const int tid = threadIdx.x;
  const int wave = tid >> 6;
  const int lane = tid & 63;
  const int lm = lane & 15;
  const int lg = lane >> 4;
  const int wm = wave >> 2;
  const int wn = wave & 3;
  const int b0 = blockIdx.x * 8;
  const int lr = lane >> 3;
  const int kcg = (lane & 7) ^ lr;         // swizzled global k-chunk for staging
  const int x7 = lm & 7;

  // ---- prologue: stage (h=0, s=0) into sB0 (hides under P compute) ----
#pragma unroll
  for (int jb = 0; jb < 3; ++jb) {
    int rb = wave + 8 * jb;                // 24 rowblocks of 8 rows
    async_copy16(sB0 + rb * 1024, wqkv + (size_t)(rb * 8 + lr) * 512 + kcg * 8);
  }

  // ---- compute P = relu(x*Wf + bf) into sA (80 real rows) ----
#pragma unroll
  for (int it = 0; it < 10; ++it) {
    int c = tid + it * 512;                // 5120 chunks: c = s*640 + r*8 + kcp
    int s = c / 640, rem = c - s * 640;
    int r = rem >> 3, kcp = rem & 7;
    int kc = kcp ^ (r & 7);
    int k = s * 64 + kc * 8;
    int bl = r / 10, f = r - bl * 10;
    float xv = x[(b0 + bl) * 10 + f];
    const float* wf = Wf + f * 512 + k;
    const float* bp = bfv + f * 512 + k;
    bf16x8 pv;
#pragma unroll
    for (int j = 0; j < 8; ++j) pv[j] = (bf16)fmaxf(xv * wf[j] + bp[j], 0.f);
    *(bf16x8*)(sA + s * 10240 + r * 128 + kcp * 16) = pv;
  }
  __syncthreads();   // full drain once: prologue staging + P writes visible

  for (int h = 0; h < 8; ++h) {
    f32x4 acc[3][3];
#pragma unroll
    for (int i = 0; i < 3; ++i)
#pragma unroll
      for (int j = 0; j < 3; ++j) { f32x4 z = {0.f, 0.f, 0.f, 0.f}; acc[i][j] = z; }

    for (int s = 0; s < 8; ++s) {
      int t = h * 8 + s;
      char* bufC = (t & 1) ? sB1 : sB0;
      char* bufN = (t & 1) ? sB0 : sB1;
      // issue next slab's staging; keep it in flight across both barriers
      if (t != 63) {
        int tn = t + 1;
        int h2 = tn >> 3, s2 = tn & 7;
        const bf16* srcb = wqkv + (size_t)h2 * 98304 + s2 * 64 + kcg * 8;
#pragma unroll
        for (int jb = 0; jb < 3; ++jb) {
          int rb = wave + 8 * jb;
          async_copy16(bufN + rb * 1024, srcb + (size_t)(rb * 8 + lr) * 512);
        }
        asm volatile("s_waitcnt vmcnt(3)" ::: "memory");  // stage(t) done; stage(t+1) in flight
      } else {
        asm volatile("s_waitcnt vmcnt(0)" ::: "memory");
      }
      __builtin_amdgcn_sched_barrier(0);
      __builtin_amdgcn_s_barrier();        // stage(t) visible to all waves
      __builtin_amdgcn_sched_barrier(0);
#pragma unroll
      for (int kk = 0; kk < 2; ++kk) {
        int ch = ((kk * 4 + lg) ^ x7) << 4;   // m&7 == n&7 == lm&7
        bf16x8 af[3], bfr[3];
#pragma unroll
        for (int mt = 0; mt < 3; ++mt)
          if (mt < 2 || wm == 0)
            af[mt] = *(const bf16x8*)(sA + s * 10240 + (wm * 48 + mt * 16 + lm) * 128 + ch);
#pragma unroll
        for (int nt = 0; nt < 3; ++nt)
          bfr[nt] = *(const bf16x8*)(bufC + (wn * 48 + nt * 16 + lm) * 128 + ch);
        __builtin_amdgcn_s_setprio(1);
#pragma unroll
        for (int mt = 0; mt < 3; ++mt)
          if (mt < 2 || wm == 0)
#pragma unroll
            for (int nt = 0; nt < 3; ++nt)
              acc[mt][nt] = __builtin_amdgcn_mfma_f32_16x16x32_bf16(af[mt], bfr[nt], acc[mt][nt], 0, 0, 0);
        __builtin_amdgcn_s_setprio(0);
      }
      asm volatile("s_waitcnt lgkmcnt(0)" ::: "memory");  // bufC reads retired
      __builtin_amdgcn_sched_barrier(0);
      __builtin_amdgcn_s_barrier();        // release bufC for re-stage
      __builtin_amdgcn_sched_barrier(0);
    }

    // ---- spill q,k (+bias) -> sQK (swizzled), v (+bias) -> vbuf ----
    {
      float bias[3];
#pragma unroll
      for (int nt = 0; nt < 3; ++nt) {
        int col = wn * 48 + nt * 16 + lm;
        bias[nt] = (col < 64) ? bq[h * 64 + col]
                 : (col < 128) ? bk[h * 64 + col - 64]
                 : bv[h * 64 + col - 128];
      }
#pragma unroll
      for (int mt = 0; mt < 3; ++mt) {
        int rowb = wm * 48 + mt * 16 + lg * 4;
        if (rowb < 80) {
#pragma unroll
          for (int r = 0; r < 4; ++r) {
            int rw = rowb + r;
#pragma unroll
            for (int nt = 0; nt < 3; ++nt) {
              int col = wn * 48 + nt * 16 + lm;
              float val = acc[mt][nt][r] + bias[nt];
              if (col < 128)
                *(bf16*)(sQK + rw * 256 + (((col >> 3) ^ (rw & 7)) << 4) + (col & 7) * 2) = (bf16)val;
              else
                vbuf[rw * 64 + (col - 128)] = (bf16)val;
            }
          }
        }
      }
    }
    __syncthreads();

    // ---- scores via MFMA (wave = local batch), softmax in-register ----
    {
      const int b = wave;
      f32x4 sv = {0.f, 0.f, 0.f, 0.f};
      const int rowa = b * 10 + lm;        // lm>=10: garbage rows, masked below
      const int x7r = rowa & 7;
#pragma unroll
      for (int kk = 0; kk < 2; ++kk) {
        bf16x8 qf = *(const bf16x8*)(sQK + rowa * 256 + (((kk * 4 + lg) ^ x7r) << 4));
        bf16x8 kf = *(const bf16x8*)(sQK + rowa * 256 + (((8 + kk * 4 + lg) ^ x7r) << 4));
        sv = __builtin_amdgcn_mfma_f32_16x16x32_bf16(qf, kf, sv, 0, 0, 0);
      }
      // C layout: row i = lg*4+r, col j = lm. softmax over j via 16-lane shuffles.
#pragma unroll
      for (int r = 0; r < 4; ++r) {
        float val = (lm < 10) ? sv[r] * 0.125f : -1e30f;   // mask pad cols
        float mx = val;
#pragma unroll
        for (int off = 1; off < 16; off <<= 1) mx = fmaxf(mx, __shfl_xor(mx, off));
        float e = __expf(val - mx);
        float ssum = e;
#pragma unroll
        for (int off = 1; off < 16; off <<= 1) ssum += __shfl_xor(ssum, off);
        int i = lg * 4 + r;
        if (i < 10 && lm < 12) scp[(b * 10 + i) * 12 + lm] = e / ssum;
      }
    }

    // ---- PV (lane <-> d), coalesced O store (wave-local) ----
    {
      const int b = wave;
      const int d = lane;                  // 0..63
      float vv[10];
#pragma unroll
      for (int j = 0; j < 10; ++j) vv[j] = (float)vbuf[(b * 10 + j) * 64 + d];
      bf16* Ob = O + ((size_t)(b0 + b) * 10) * 512 + h * 64 + d;
#pragma unroll
      for (int i = 0; i < 10; ++i) {
        const float* ar = scp + (b * 10 + i) * 12;
        f32x4 a0 = *(const f32x4*)ar;
        f32x4 a1 = *(const f32x4*)(ar + 4);
        float o = a0[0] * vv[0] + a0[1] * vv[1] + a0[2] * vv[2] + a0[3] * vv[3]
                + a1[0] * vv[4] + a1[1] * vv[5] + a1[2] * vv[6] + a1[3] * vv[7]
                + ar[8] * vv[8] + ar[9] * vv[9];
        Ob[(size_t)i * 512] = (bf16)o;     // 64 lanes x 2B = 128B contiguous
      }
    }
    __syncthreads();  // protect vbuf/scp (in sB1) before next head's staging
  }

  // ================= Phase 2: O @ Wo^T + bo -> LN -> sum over F =================
  // BK=32, dbuf A+B, raw barriers + counted vmcnt. Paired-row LDS layout:
  // rows 2r,2r+1 share a 128B line; granule g of row R at
  //   (R>>1)*128 + (R&1)*64 + ((g ^ ((R>>1)&3))<<4)
  // staged via linear 1024B copies with pre-swizzled global source.
  {
    char* Ab0 = smem;
    char* Ab1 = smem + 5120;
    char* Bb0 = smem + 10240;
    char* Bb1 = smem + 43008;
    float* partial = (float*)(smem + 145920); // [80][4][2]
    float* stats   = (float*)(smem + 148992); // [80][2]
    const char* Ob = (const char*)(O + (size_t)blockIdx.x * 80 * 512);
    const char* Wb = (const char*)wob;

    const int srow  = lane >> 2;                       // source row within 16-row copy
    const int sgran = (lane & 3) ^ ((lane >> 3) & 3);  // pre-swizzled source granule

    f32x4 acc[3][8];
#pragma unroll
    for (int i = 0; i < 3; ++i)
#pragma unroll
      for (int j = 0; j < 8; ++j) { f32x4 z = {0.f, 0.f, 0.f, 0.f}; acc[i][j] = z; }

    // stage slab s into (AbN, BbN): B 4 copies/wave, A 1 copy for waves 0-4
#define STAGE2(AbN, BbN, s_)                                                     \
    {                                                                            \
      size_t co = (size_t)(s_) * 64 + sgran * 16;                                \
      _Pragma("unroll")                                                          \
      for (int j = 0; j < 4; ++j) {                                              \
        int R0 = (wave * 4 + j) * 16;                                            \
        async_copy16((BbN) + R0 * 64, Wb + (size_t)(R0 + srow) * 1024 + co);     \
      }                                                                          \
      if (wave < 5) {                                                            \
        int R0 = wave * 16;                                                      \
        async_copy16((AbN) + R0 * 64, Ob + (size_t)(R0 + srow) * 1024 + co);     \
      }                                                                          \
    }

    STAGE2(Ab0, Bb0, 0);                   // prologue

    for (int s = 0; s < 16; ++s) {
      char* AbC = (s & 1) ? Ab1 : Ab0;
      char* BbC = (s & 1) ? Bb1 : Bb0;
      char* AbN = (s & 1) ? Ab0 : Ab1;
      char* BbN = (s & 1) ? Bb0 : Bb1;
      if (s != 15) {
        STAGE2(AbN, BbN, s + 1);
        if (wave < 5) asm volatile("s_waitcnt vmcnt(5)" ::: "memory");
        else          asm volatile("s_waitcnt vmcnt(4)" ::: "memory");
      } else {
        asm volatile("s_waitcnt vmcnt(0)" ::: "memory");
      }
      __builtin_amdgcn_sched_barrier(0);
      __builtin_amdgcn_s_barrier();        // slab s visible
      __builtin_amdgcn_sched_barrier(0);

      bf16x8 a2[3], b2[8];
#pragma unroll
      for (int mt = 0; mt < 3; ++mt)
        if (mt < 2 || wm == 0) {
          int m = wm * 48 + mt * 16 + lm;
          a2[mt] = *(const bf16x8*)(AbC + (m >> 1) * 128 + (m & 1) * 64 + (((lg ^ ((m >> 1) & 3))) << 4));
        }
#pragma unroll
      for (int nt = 0; nt < 8; ++nt) {
        int n = wn * 128 + nt * 16 + lm;
        b2[nt] = *(const bf16x8*)(BbC + (n >> 1) * 128 + (n & 1) * 64 + (((lg ^ ((n >> 1) & 3))) << 4));
      }
      __builtin_amdgcn_s_setprio(1);
#pragma unroll
      for (int mt = 0; mt < 3; ++mt)
        if (mt < 2 || wm == 0)
#pragma unroll
          for (int nt = 0; nt < 8; ++nt)
            acc[mt][nt] = __builtin_amdgcn_mfma_f32_16x16x32_bf16(a2[mt], b2[nt], acc[mt][nt], 0, 0, 0);
      __builtin_amdgcn_s_setprio(0);

      asm volatile("s_waitcnt lgkmcnt(0)" ::: "memory");
      __builtin_amdgcn_sched_barrier(0);
      __builtin_amdgcn_s_barrier();        // release slab s buffers
      __builtin_amdgcn_sched_barrier(0);
    }

    // + bias
#pragma unroll
    for (int nt = 0; nt < 8; ++nt) {
      float bb = bo[wn * 128 + nt * 16 + lm];
#pragma unroll
      for (int mt = 0; mt < 3; ++mt)
#pragma unroll
        for (int r = 0; r < 4; ++r) acc[mt][nt][r] += bb;
    }

    // per-row mean/var: lane-local over 8 nt, then xor-shuffle across 16-lane col group
#pragma unroll
    for (int mt = 0; mt < 3; ++mt)
#pragma unroll
      for (int r = 0; r < 4; ++r) {
        float s1 = 0.f, s2 = 0.f;
#pragma unroll
        for (int nt = 0; nt < 8; ++nt) { float v = acc[mt][nt][r]; s1 += v; s2 += v * v; }
#pragma unroll
        for (int off = 1; off < 16; off <<= 1) {
          s1 += __shfl_xor(s1, off);
          s2 += __shfl_xor(s2, off);
        }
        if (lm == 0) {
          int row = wm * 48 + mt * 16 + lg * 4 + r;
          if (row < 80) {
            partial[(row * 4 + wn) * 2]     = s1;
            partial[(row * 4 + wn) * 2 + 1] = s2;
          }
        }
      }
    __syncthreads();
    if (tid < 80) {
      float s1 = 0.f, s2 = 0.f;
#pragma unroll
      for (int w = 0; w < 4; ++w) {
        s1 += partial[(tid * 4 + w) * 2];
        s2 += partial[(tid * 4 + w) * 2 + 1];
      }
      float mu = s1 * (1.f / 512.f);
      float var = s2 * (1.f / 512.f) - mu * mu;
      stats[tid * 2]     = mu;
      stats[tid * 2 + 1] = rsqrtf(var + EPS);
    }
    __syncthreads();
    // normalized values -> LDS bf16 (GEMM buffers dead), stride 520
    bf16* lnb = (bf16*)smem;
#pragma unroll
    for (int mt = 0; mt < 3; ++mt)
#pragma unroll
      for (int r = 0; r < 4; ++r) {
        int row = wm * 48 + mt * 16 + lg * 4 + r;
        if (row < 80) {
          float mu = stats[row * 2], rr = stats[row * 2 + 1];
#pragma unroll
          for (int nt = 0; nt < 8; ++nt) {
            int col = wn * 128 + nt * 16 + lm;
            lnb[row * 520 + col] = (bf16)((acc[mt][nt][r] - mu) * rr);
          }
        }
      }
    __syncthreads();
    // out[b,n] = gamma[n]*sum_f lnv + 10*beta[n]
#pragma unroll
    for (int u = 0; u < 8; ++u) {
      int id = tid + u * 512;              // 4096 outputs: 8b x 512n
      int b = id >> 9, n = id & 511;
      float ssum = 0.f;
#pragma unroll
      for (int f = 0; f < 10; ++f) ssum += (float)lnb[(b * 10 + f) * 520 + n];
      out[((size_t)blockIdx.x * 8 + b) * 512 + n] = gamma[n] * ssum + 10.f * beta[n];
    }
  }
#undef STAGE2
}

extern "C" void kernel_launch(void* const* d_in, const int* in_sizes, int n_in,
                              void* d_out, int out_size, void* d_ws, size_t ws_size,
                              hipStream_t stream) {
  const float* x     = (const float*)d_in[0];
  const float* Wf    = (const float*)d_in[1];
  const float* bfv   = (const float*)d_in[2];
  const float* Wq    = (const float*)d_in[3];
  const float* Wk    = (const float*)d_in[4];
  const float* Wv    = (const float*)d_in[5];
  const float* bq    = (const float*)d_in[6];
  const float* bk    = (const float*)d_in[7];
  const float* bv    = (const float*)d_in[8];
  const float* Wo    = (const float*)d_in[9];
  const float* bo    = (const float*)d_in[10];
  const float* gamma = (const float*)d_in[11];
  const float* beta  = (const float*)d_in[12];
  float* out = (float*)d_out;

  char* ws = (char*)d_ws;
  bf16* O    = (bf16*)ws;                              // 167,772,160 B
  bf16* wqkv = (bf16*)(ws + O_BYTES);                  // 1,572,864 B
  bf16* wob  = (bf16*)(ws + O_BYTES + WQKV_BYTES);     // 524,288 B

  pack_weights<<<1024, 256, 0, stream>>>(Wq, Wk, Wv, Wo, wqkv, wob);
  kern_fused<<<2048, 512, 0, stream>>>(x, Wf, bfv, wqkv, bq, bk, bv, O,
                                       wob, bo, gamma, beta, out);
}